// Round 8
// baseline (122.595 us; speedup 1.0000x reference)
//
#include <hip/hip_runtime.h>
#include <hip/hip_bf16.h>

typedef __attribute__((ext_vector_type(8))) short bf16x8;
typedef __attribute__((ext_vector_type(4))) float floatx4;

#define NB 128
#define NT 256
#define NC 384
#define NH 8
#define ND 48
#define CPLANE (128 * 8 * 256 * 48)  // elems per qkv component plane

static __device__ __forceinline__ unsigned short f2bf(float f) {
  __hip_bfloat16 h = __float2bfloat16(f);
  return __builtin_bit_cast(unsigned short, h);
}

static __device__ __forceinline__ void gload16(const unsigned short* g, unsigned short* l) {
  __builtin_amdgcn_global_load_lds(
      (const __attribute__((address_space(1))) void*)g,
      (__attribute__((address_space(3))) void*)l, 16, 0, 0);
}

// ---------------- Prep: W_qkv^T -> [1152][384] bf16, W_proj^T (gate folded) -> [384][384],
//                  x fp32 -> bf16.
__global__ __launch_bounds__(256) void k_prep(const float* __restrict__ x,
                                              const float* __restrict__ Wq,
                                              const float* __restrict__ Wp,
                                              const float* __restrict__ gate,
                                              unsigned short* __restrict__ xbf,
                                              unsigned short* __restrict__ WqT,
                                              unsigned short* __restrict__ WpT) {
  const int blk = blockIdx.x;
  const int t = threadIdx.x;
  if (blk < 144) {
    __shared__ float T[64][65];
    const float* src;
    unsigned short* dst;
    int N, kt, nt;
    const bool isWp = (blk >= 108);
    if (!isWp) { src = Wq; dst = WqT; N = 1152; kt = blk / 18; nt = blk % 18; }
    else { int b2 = blk - 108; src = Wp; dst = WpT; N = 384; kt = b2 / 6; nt = b2 % 6; }
    const int k0 = kt * 64, n0 = nt * 64;
    const int r = t >> 2, c = (t & 3) * 16;
    const float* s = src + (size_t)(k0 + r) * N + n0 + c;
#pragma unroll
    for (int i = 0; i < 4; ++i) *(float4*)&T[r][c + i * 4] = ((const float4*)s)[i];
    __syncthreads();
    float gv[16];
    if (isWp) {
#pragma unroll
      for (int i = 0; i < 4; ++i) *(float4*)&gv[i * 4] = ((const float4*)(gate + k0 + c))[i];
    } else {
#pragma unroll
      for (int i = 0; i < 16; ++i) gv[i] = 1.f;
    }
    unsigned short o[16];
#pragma unroll
    for (int i = 0; i < 16; ++i) o[i] = f2bf(T[c + i][r] * gv[i]);
    unsigned short* dp = dst + (size_t)(n0 + r) * 384 + k0 + c;
    *(bf16x8*)dp = *(bf16x8*)&o[0];
    *(bf16x8*)(dp + 8) = *(bf16x8*)&o[8];
  } else {
    const int n8 = (NB * NT * NC) / 8;
    int idx = (blk - 144) * 256 + t;
    const int stride = (gridDim.x - 144) * 256;
    for (; idx < n8; idx += stride) {
      const float* s = x + (size_t)idx * 8;
      float v[8];
      *(float4*)&v[0] = ((const float4*)s)[0];
      *(float4*)&v[4] = ((const float4*)s)[1];
      bf16x8 p;
#pragma unroll
      for (int i = 0; i < 8; ++i) p[i] = f2bf(v[i]);
      *(bf16x8*)(xbf + (size_t)idx * 8) = p;
    }
  }
}

// ====== barrier-free GEMM core pieces (wave-private A staging, shared read-only B) ======
// A: 64 rows x 32 k, per-wave double-buffered in private LDS slice (linear + source XOR swz)
#define STAGE_A(k0, buf)                                                              \
  {                                                                                   \
    _Pragma("unroll") for (int g = 0; g < 4; ++g) {                                   \
      const int r_ = (lane >> 2) + 16 * g;                                            \
      gload16(Ag + (size_t)r_ * 384 + (k0) + 8 * ((lane & 3) ^ ((r_ >> 1) & 3)),      \
              Asl + (buf)*2048 + g * 512);                                            \
    }                                                                                 \
  }

// B cooperative one-time stage: 48 rows x 384 k, elem = r*384 + 8*(kchunk ^ (r&7))
#define STAGE_B(WT)                                                                   \
  {                                                                                   \
    _Pragma("unroll") for (int cc = 0; cc < 9; ++cc) {                                \
      const int idx_ = cc * 256 + t;                                                  \
      const int r_ = idx_ / 48, kc_ = idx_ - r_ * 48;                                 \
      bf16x8 v_ = *(const bf16x8*)((WT) + (size_t)(n0 + r_) * 384 + kc_ * 8);         \
      *(bf16x8*)&Bs[r_ * 384 + 8 * (kc_ ^ (r_ & 7))] = v_;                            \
    }                                                                                 \
  }

// K-loop: 12 iters, no barriers; per-wave counted vmcnt for own A DMA.
#define GEMM_NOBAR()                                                                  \
  STAGE_A(0, 0);                                                                      \
  STAGE_A(32, 1);                                                                     \
  __syncthreads(); /* B visible; A(0),A(1) drained */                                 \
  _Pragma("unroll") for (int t_ = 0; t_ < 12; ++t_) {                                 \
    if (t_ < 11) asm volatile("s_waitcnt vmcnt(4)" ::: "memory");                     \
    else         asm volatile("s_waitcnt vmcnt(0)" ::: "memory");                     \
    __builtin_amdgcn_sched_barrier(0);                                                \
    const unsigned short* Ac_ = Asl + (t_ & 1) * 2048;                                \
    bf16x8 a_[4], b_[3];                                                              \
    _Pragma("unroll") for (int mt = 0; mt < 4; ++mt) {                                \
      const int R = mt * 16 + lq;                                                     \
      a_[mt] = *(const bf16x8*)&Ac_[R * 32 + 8 * (lg ^ ((R >> 1) & 3))];              \
    }                                                                                 \
    _Pragma("unroll") for (int nt = 0; nt < 3; ++nt) {                                \
      const int R = nt * 16 + lq;                                                     \
      b_[nt] = *(const bf16x8*)&Bs[R * 384 + 8 * ((t_ * 4 + lg) ^ (R & 7))];          \
    }                                                                                 \
    asm volatile("s_waitcnt lgkmcnt(0)" ::: "memory");                                \
    __builtin_amdgcn_sched_barrier(0);                                                \
    if (t_ < 10) STAGE_A((t_ + 2) * 32, t_ & 1);                                      \
    _Pragma("unroll") for (int mt = 0; mt < 4; ++mt)                                  \
      _Pragma("unroll") for (int nt = 0; nt < 3; ++nt)                                \
        acc[mt][nt] = __builtin_amdgcn_mfma_f32_16x16x32_bf16(a_[mt], b_[nt], acc[mt][nt], 0, 0, 0); \
  }

// ---------------- Kernel 1: qkv = xb @ WqT^T + b_qkv -> packed bf16 [3][B][H][T][48]
// block = 256 rows x 48 cols (one comp,head); 4 waves x 64 rows; no K-loop barriers.
__global__ __launch_bounds__(256) void k_qkv(const unsigned short* __restrict__ xb,
                                             const unsigned short* __restrict__ WqT,
                                             const float* __restrict__ bq,
                                             unsigned short* __restrict__ qkv) {
  __shared__ __align__(16) unsigned short Bs[48 * 384];   // 36 KB, XOR-swizzled
  __shared__ __align__(16) unsigned short As[4 * 4096];   // 4 waves x (2 x 64x32)
  const int t = threadIdx.x, lane = t & 63, w = t >> 6;
  const int lq = lane & 15, lg = lane >> 4;
  const int swz = (blockIdx.x & 7) * 384 + (blockIdx.x >> 3);  // 3072 = 8*384
  const int mblk = swz / 24, nblk = swz % 24;
  const int m0 = mblk * 256, n0 = nblk * 48;
  const unsigned short* Ag = xb + (size_t)(m0 + w * 64) * 384;
  unsigned short* Asl = As + w * 4096;

  STAGE_B(WqT);
  floatx4 acc[4][3] = {};
  GEMM_NOBAR();

  // epilogue: +bias, transpose in own LDS slice, contiguous packed store
  const int comp = nblk >> 3, h = nblk & 7;
#pragma unroll
  for (int nt = 0; nt < 3; ++nt) {
    const float bias = bq[n0 + nt * 16 + lq];
#pragma unroll
    for (int mt = 0; mt < 4; ++mt)
#pragma unroll
      for (int j = 0; j < 4; ++j) {
        const int r = mt * 16 + lg * 4 + j;
        Asl[r * 48 + nt * 16 + lq] = f2bf(acc[mt][nt][j] + bias);
      }
  }
  asm volatile("s_waitcnt lgkmcnt(0)" ::: "memory");
  __builtin_amdgcn_sched_barrier(0);
  const size_t base = (size_t)comp * CPLANE + ((size_t)(mblk * 8 + h) * 256 + w * 64) * 48;
#pragma unroll
  for (int i = 0; i < 6; ++i) {
    bf16x8 v = *(const bf16x8*)&Asl[i * 512 + lane * 8];
    *(bf16x8*)(qkv + base + i * 512 + lane * 8) = v;
  }
}

// ---------------- Kernel 3: out = attg @ WpT^T + b_proj (fp32 out; gate pre-folded)
__global__ __launch_bounds__(256) void k_proj(const unsigned short* __restrict__ A,
                                              const unsigned short* __restrict__ WpT,
                                              const float* __restrict__ bp,
                                              float* __restrict__ out) {
  __shared__ __align__(16) unsigned short Bs[48 * 384];
  __shared__ __align__(16) unsigned short As[4 * 4096];
  const int t = threadIdx.x, lane = t & 63, w = t >> 6;
  const int lq = lane & 15, lg = lane >> 4;
  const int swz = (blockIdx.x & 7) * 128 + (blockIdx.x >> 3);  // 1024 = 8*128
  const int mblk = swz / 8, nblk = swz % 8;
  const int m0 = mblk * 256, n0 = nblk * 48;
  const unsigned short* Ag = A + (size_t)(m0 + w * 64) * 384;
  unsigned short* Asl = As + w * 4096;

  STAGE_B(WpT);
  floatx4 acc[4][3] = {};
  GEMM_NOBAR();

#pragma unroll
  for (int nt = 0; nt < 3; ++nt) {
    const int col = n0 + nt * 16 + lq;
    const float bias = bp[col];
#pragma unroll
    for (int mt = 0; mt < 4; ++mt)
#pragma unroll
      for (int j = 0; j < 4; ++j) {
        const int row = m0 + w * 64 + mt * 16 + lg * 4 + j;
        out[(size_t)row * 384 + col] = acc[mt][nt][j] + bias;
      }
  }
}

// ---------------- Kernel 2: windowed causal attention, packed qkv in, bf16 out [B][T][C]
__global__ __launch_bounds__(256) void k_attn(const unsigned short* __restrict__ qkv,
                                              unsigned short* __restrict__ attg) {
  __shared__ __align__(16) unsigned short Ks[128 * 72];      // [key][hd pad 64->72]
  __shared__ __align__(16) unsigned short Vt[48 * 152];      // [d][key pad 144->152]
  __shared__ __align__(16) unsigned short Ps[4 * 16 * 104];  // per-wave P [q][key pad]
  const int t = threadIdx.x;
  const int blk = blockIdx.x;
  const int tile = blk & 3;
  const int bh = blk >> 2;
  const int b = bh >> 3, h = bh & 7;
  const int base = tile * 64;
  const size_t kvoff = (size_t)bh * NT * ND;
  const unsigned short* qptr = qkv + kvoff;
  const unsigned short* kptr = qkv + (size_t)CPLANE + kvoff;
  const unsigned short* vptr = qkv + (size_t)2 * CPLANE + kvoff;

  if (t < 48) {
    bf16x8 z = {};
    *(bf16x8*)&Vt[t * 152 + 128] = z;
    *(bf16x8*)&Vt[t * 152 + 136] = z;
  }
  if (t < 128) {
    const int r = t, ka = base - 64 + r;
    unsigned short* dst = &Ks[r * 72];
    if (ka >= 0) {
      const unsigned short* src = kptr + (size_t)ka * ND;
#pragma unroll
      for (int i = 0; i < 6; ++i) *(bf16x8*)(dst + i * 8) = *(const bf16x8*)(src + i * 8);
      bf16x8 z = {};
      *(bf16x8*)(dst + 48) = z;
      *(bf16x8*)(dst + 56) = z;
    } else {
      bf16x8 z = {};
#pragma unroll
      for (int i = 0; i < 8; ++i) *(bf16x8*)(dst + i * 8) = z;
    }
  } else {
    const int r = t - 128, ka = base - 64 + r;
    if (ka >= 0) {
      const unsigned short* src = vptr + (size_t)ka * ND;
      bf16x8 vv[6];
#pragma unroll
      for (int i = 0; i < 6; ++i) vv[i] = *(const bf16x8*)(src + i * 8);
#pragma unroll
      for (int i = 0; i < 6; ++i)
#pragma unroll
        for (int j = 0; j < 8; ++j)
          Vt[(i * 8 + j) * 152 + r] = (unsigned short)vv[i][j];
    } else {
#pragma unroll
      for (int d = 0; d < 48; ++d) Vt[d * 152 + r] = 0;
    }
  }
  __syncthreads();

  const int lane = t & 63, w = t >> 6;
  const int lq = lane & 15, lg = lane >> 4;
  const int qs = base + w * 16;

  const unsigned short* qrow = qptr + (size_t)(qs + lq) * ND;
  bf16x8 aq0 = *(const bf16x8*)(qrow + lg * 8);
  bf16x8 aq1 = {};
  if (lg < 2) aq1 = *(const bf16x8*)(qrow + 32 + lg * 8);

  floatx4 s[5];
#pragma unroll
  for (int kt = 0; kt < 5; ++kt) {
    const unsigned short* kr = &Ks[(w * 16 + kt * 16 + lq) * 72];
    bf16x8 kb0 = *(const bf16x8*)(kr + lg * 8);
    bf16x8 kb1 = *(const bf16x8*)(kr + 32 + lg * 8);
    floatx4 z = {};
    z = __builtin_amdgcn_mfma_f32_16x16x32_bf16(aq0, kb0, z, 0, 0, 0);
    z = __builtin_amdgcn_mfma_f32_16x16x32_bf16(aq1, kb1, z, 0, 0, 0);
    s[kt] = z;
  }

  const float scale = 0.14433756729740643f;  // 1/sqrt(48)
  floatx4 pj[5];
#pragma unroll
  for (int j = 0; j < 4; ++j) {
    const int qa = qs + lg * 4 + j;
    float mx = -1e30f;
    float sv[5];
    bool ok[5];
#pragma unroll
    for (int kt = 0; kt < 5; ++kt) {
      const int ka = base - 64 + w * 16 + kt * 16 + lq;
      sv[kt] = s[kt][j] * scale;
      ok[kt] = (ka >= 0) && (ka <= qa) && (qa - ka <= 64);
      if (ok[kt]) mx = fmaxf(mx, sv[kt]);
    }
#pragma unroll
    for (int dd = 1; dd < 16; dd <<= 1) mx = fmaxf(mx, __shfl_xor(mx, dd));
    float sum = 0.f;
#pragma unroll
    for (int kt = 0; kt < 5; ++kt) {
      float p = ok[kt] ? __expf(sv[kt] - mx) : 0.f;
      pj[kt][j] = p;
      sum += p;
    }
#pragma unroll
    for (int dd = 1; dd < 16; dd <<= 1) sum += __shfl_xor(sum, dd);
    const float inv = 1.f / sum;
#pragma unroll
    for (int kt = 0; kt < 5; ++kt) pj[kt][j] *= inv;
  }

  unsigned short* pw = &Ps[w * 16 * 104];
#pragma unroll
  for (int kt = 0; kt < 5; ++kt)
#pragma unroll
    for (int j = 0; j < 4; ++j)
      pw[(lg * 4 + j) * 104 + kt * 16 + lq] = f2bf(pj[kt][j]);
#pragma unroll
  for (int j = 0; j < 4; ++j) pw[lq * 104 + 80 + lg * 4 + j] = 0;

  floatx4 o[3] = {};
#pragma unroll
  for (int c = 0; c < 3; ++c) {
    bf16x8 ap = *(const bf16x8*)&pw[lq * 104 + c * 32 + lg * 8];
#pragma unroll
    for (int nt = 0; nt < 3; ++nt) {
      bf16x8 av = *(const bf16x8*)&Vt[(nt * 16 + lq) * 152 + w * 16 + c * 32 + lg * 8];
      o[nt] = __builtin_amdgcn_mfma_f32_16x16x32_bf16(ap, av, o[nt], 0, 0, 0);
    }
  }
#pragma unroll
  for (int nt = 0; nt < 3; ++nt) {
    const int d = nt * 16 + lq;
    const int c = h * ND + d;
#pragma unroll
    for (int j = 0; j < 4; ++j) {
      const int tt = qs + lg * 4 + j;
      attg[((size_t)b * NT + tt) * NC + c] = f2bf(o[nt][j]);
    }
  }
}

extern "C" void kernel_launch(void* const* d_in, const int* in_sizes, int n_in,
                              void* d_out, int out_size, void* d_ws, size_t ws_size,
                              hipStream_t stream) {
  const float* x    = (const float*)d_in[0];
  const float* Wq   = (const float*)d_in[1];
  const float* bq   = (const float*)d_in[2];
  const float* Wp   = (const float*)d_in[3];
  const float* bp   = (const float*)d_in[4];
  const float* gate = (const float*)d_in[5];

  const size_t nx = (size_t)NB * NT * NC;                // 12,582,912
  unsigned short* attg = (unsigned short*)d_ws;
  unsigned short* xbf  = attg + nx;
  unsigned short* qkvp = xbf + nx;                       // packed [3][B][H][T][48]
  unsigned short* WqT  = qkvp + (size_t)3 * CPLANE;
  unsigned short* WpT  = WqT + (size_t)384 * 1152;
  float* out = (float*)d_out;

  k_prep<<<dim3(1680), 256, 0, stream>>>(x, Wq, Wp, gate, xbf, WqT, WpT);
  k_qkv<<<dim3(3072), 256, 0, stream>>>(xbf, WqT, bq, qkvp);
  k_attn<<<dim3(4096), 256, 0, stream>>>(qkvp, attg);
  k_proj<<<dim3(1024), 256, 0, stream>>>(attg, WpT, bp, out);
}

// Round 9
// 121.709 us; speedup vs baseline: 1.0073x; 1.0073x over previous
//
#include <hip/hip_runtime.h>
#include <hip/hip_bf16.h>

typedef __attribute__((ext_vector_type(8))) short bf16x8;
typedef __attribute__((ext_vector_type(4))) float floatx4;

#define NB 128
#define NT 256
#define NC 384
#define NH 8
#define ND 48
#define CPLANE (128 * 8 * 256 * 48)  // elems per qkv component plane

static __device__ __forceinline__ unsigned short f2bf(float f) {
  __hip_bfloat16 h = __float2bfloat16(f);
  return __builtin_bit_cast(unsigned short, h);
}

static __device__ __forceinline__ void gload16(const unsigned short* g, unsigned short* l) {
  __builtin_amdgcn_global_load_lds(
      (const __attribute__((address_space(1))) void*)g,
      (__attribute__((address_space(3))) void*)l, 16, 0, 0);
}

// ---------------- Prep: W_qkv^T -> [1152][384] bf16, W_proj^T (gate folded) -> [384][384],
//                  x fp32 -> bf16.
__global__ __launch_bounds__(256) void k_prep(const float* __restrict__ x,
                                              const float* __restrict__ Wq,
                                              const float* __restrict__ Wp,
                                              const float* __restrict__ gate,
                                              unsigned short* __restrict__ xbf,
                                              unsigned short* __restrict__ WqT,
                                              unsigned short* __restrict__ WpT) {
  const int blk = blockIdx.x;
  const int t = threadIdx.x;
  if (blk < 144) {
    __shared__ float T[64][65];
    const float* src;
    unsigned short* dst;
    int N, kt, nt;
    const bool isWp = (blk >= 108);
    if (!isWp) { src = Wq; dst = WqT; N = 1152; kt = blk / 18; nt = blk % 18; }
    else { int b2 = blk - 108; src = Wp; dst = WpT; N = 384; kt = b2 / 6; nt = b2 % 6; }
    const int k0 = kt * 64, n0 = nt * 64;
    const int r = t >> 2, c = (t & 3) * 16;
    const float* s = src + (size_t)(k0 + r) * N + n0 + c;
#pragma unroll
    for (int i = 0; i < 4; ++i) *(float4*)&T[r][c + i * 4] = ((const float4*)s)[i];
    __syncthreads();
    float gv[16];
    if (isWp) {
#pragma unroll
      for (int i = 0; i < 4; ++i) *(float4*)&gv[i * 4] = ((const float4*)(gate + k0 + c))[i];
    } else {
#pragma unroll
      for (int i = 0; i < 16; ++i) gv[i] = 1.f;
    }
    unsigned short o[16];
#pragma unroll
    for (int i = 0; i < 16; ++i) o[i] = f2bf(T[c + i][r] * gv[i]);
    unsigned short* dp = dst + (size_t)(n0 + r) * 384 + k0 + c;
    *(bf16x8*)dp = *(bf16x8*)&o[0];
    *(bf16x8*)(dp + 8) = *(bf16x8*)&o[8];
  } else {
    const int n8 = (NB * NT * NC) / 8;
    int idx = (blk - 144) * 256 + t;
    const int stride = (gridDim.x - 144) * 256;
    for (; idx < n8; idx += stride) {
      const float* s = x + (size_t)idx * 8;
      float v[8];
      *(float4*)&v[0] = ((const float4*)s)[0];
      *(float4*)&v[4] = ((const float4*)s)[1];
      bf16x8 p;
#pragma unroll
      for (int i = 0; i < 8; ++i) p[i] = f2bf(v[i]);
      *(bf16x8*)(xbf + (size_t)idx * 8) = p;
    }
  }
}

// ====== r7-proven staging: 128x32 tile, source XOR-swizzle, linear LDS dest ======
#define STAGE_G(Ag, Bg, k0, buf)                                                     \
  {                                                                                  \
    const int r0_ = (lane >> 2), sw0_ = 8 * ((lane & 3) ^ ((r0_ >> 1) & 3));         \
    const int r1_ = r0_ + 16,    sw1_ = 8 * ((lane & 3) ^ ((r1_ >> 1) & 3));         \
    gload16((Ag) + (size_t)r0_ * 384 + (k0) + sw0_, As + (buf)*4096 + (w * 32) * 32);  \
    gload16((Ag) + (size_t)r1_ * 384 + (k0) + sw1_, As + (buf)*4096 + (w * 32 + 16) * 32); \
    gload16((Bg) + (size_t)r0_ * 384 + (k0) + sw0_, Bs + (buf)*4096 + (w * 32) * 32);  \
    gload16((Bg) + (size_t)r1_ * 384 + (k0) + sw1_, Bs + (buf)*4096 + (w * 32 + 16) * 32); \
  }

// one pipeline iteration: wait, barrier, stage(future), 8 frag reads, 16 MFMA
#define QITER(vmstr, gmod3, STG)                                                     \
  asm volatile("s_waitcnt vmcnt(" vmstr ")" ::: "memory");                           \
  __builtin_amdgcn_s_barrier();                                                      \
  STG;                                                                               \
  {                                                                                  \
    const unsigned short* Ac_ = As + (gmod3) * 4096;                                 \
    const unsigned short* Bc_ = Bs + (gmod3) * 4096;                                 \
    bf16x8 a_[4], b_[4];                                                             \
    _Pragma("unroll") for (int mt = 0; mt < 4; ++mt) {                               \
      const int R = wm * 64 + mt * 16 + lq;                                          \
      a_[mt] = *(const bf16x8*)&Ac_[R * 32 + 8 * (lg ^ ((R >> 1) & 3))];             \
    }                                                                                \
    _Pragma("unroll") for (int nt = 0; nt < 4; ++nt) {                               \
      const int R = wn * 64 + nt * 16 + lq;                                          \
      b_[nt] = *(const bf16x8*)&Bc_[R * 32 + 8 * (lg ^ ((R >> 1) & 3))];             \
    }                                                                                \
    _Pragma("unroll") for (int mt = 0; mt < 4; ++mt)                                 \
      _Pragma("unroll") for (int nt = 0; nt < 4; ++nt)                               \
        acc[mt][nt] = __builtin_amdgcn_mfma_f32_16x16x32_bf16(a_[mt], b_[nt], acc[mt][nt], 0, 0, 0); \
  }

// epilogue: wave-local transpose in dying buf2 slice -> 8x 16B packed stores.
// barrier first: protects buf2 (other waves' frag reads) before clobber.
#define QEPI(m0)                                                                     \
  __builtin_amdgcn_s_barrier();                                                      \
  {                                                                                  \
    unsigned short* Ew = ((w < 2) ? As : Bs) + 2 * 4096 + (w & 1) * 2048;            \
    _Pragma("unroll") for (int p = 0; p < 4; ++p) {                                  \
      _Pragma("unroll") for (int nt = 0; nt < 4; ++nt)                               \
        _Pragma("unroll") for (int j = 0; j < 4; ++j)                                \
          Ew[(lg * 4 + j) * 72 + nt * 16 + lq] = f2bf(acc[p][nt][j] + bias[nt]);     \
      asm volatile("s_waitcnt lgkmcnt(0)" ::: "memory");                             \
      __builtin_amdgcn_sched_barrier(0);                                             \
      _Pragma("unroll") for (int cc = 0; cc < 2; ++cc) {                             \
        const int c = cc * 64 + lane;                                                \
        const int r16 = c >> 3, k8 = c & 7;                                          \
        bf16x8 v = *(const bf16x8*)&Ew[r16 * 72 + k8 * 8];                           \
        const int lc = n0 - comp * 384 + wn * 64 + k8 * 8;                           \
        const int hh = lc / 48, d0 = lc - hh * 48;                                   \
        const int R = (m0) + wm * 64 + p * 16 + r16;                                 \
        *(bf16x8*)(qkv + (size_t)comp * CPLANE +                                     \
                   (((size_t)((R >> 8) * 8 + hh) * 256 + (R & 255)) * 48 + d0)) = v; \
      }                                                                              \
      asm volatile("s_waitcnt lgkmcnt(0)" ::: "memory");                             \
      __builtin_amdgcn_sched_barrier(0);                                             \
    }                                                                                \
  }

// ---------------- Kernel 1: qkv GEMM, persistent 2 m-tiles/block, packed output.
// vmcnt ledger (per wave; bias=4 oldest, completes first):
//  g<11: out = L(g)4+L(g+1)4 -> vmcnt(4) waits L(g).
//  g=11: compute; [bar]; EPI (8 stores); stage L13.
//  g=12: out = L12(4)+S(8)+L13(4)=16 -> vmcnt(12) waits L12 (no store wait).
//  g=13: out = S8+L13+L14 -> vmcnt(4) waits S+L13 (stores ~2 iters old).
//  g>=14 normal; g=23 vmcnt(0).
__global__ __launch_bounds__(256) void k_qkv(const unsigned short* __restrict__ xb,
                                             const unsigned short* __restrict__ WqT,
                                             const float* __restrict__ bq,
                                             unsigned short* __restrict__ qkv) {
  __shared__ __align__(16) unsigned short As[3 * 4096];
  __shared__ __align__(16) unsigned short Bs[3 * 4096];
  const int t = threadIdx.x, lane = t & 63, w = t >> 6;
  const int wm = w >> 1, wn = w & 1;
  const int lq = lane & 15, lg = lane >> 4;
  const int swz = (blockIdx.x & 7) * 144 + (blockIdx.x >> 3);  // 1152 = 8*144
  const int mp = swz / 9, nblk = swz % 9;
  const int n0 = nblk * 128;
  const int comp = n0 / 384;
  const unsigned short* Ag0 = xb + (size_t)(mp * 256 + w * 32) * 384;
  const unsigned short* Ag1 = Ag0 + (size_t)128 * 384;
  const unsigned short* Bg = WqT + (size_t)(n0 + w * 32) * 384;

  float bias[4];
#pragma unroll
  for (int nt = 0; nt < 4; ++nt) bias[nt] = bq[n0 + wn * 64 + nt * 16 + lq];

  floatx4 acc[4][4] = {};
  STAGE_G(Ag0, Bg, 0, 0);
  STAGE_G(Ag0, Bg, 32, 1);
  QITER("4", 0, STAGE_G(Ag0, Bg, 64, 2));    // g=0
  QITER("4", 1, STAGE_G(Ag0, Bg, 96, 0));    // g=1
  QITER("4", 2, STAGE_G(Ag0, Bg, 128, 1));   // g=2
  QITER("4", 0, STAGE_G(Ag0, Bg, 160, 2));   // g=3
  QITER("4", 1, STAGE_G(Ag0, Bg, 192, 0));   // g=4
  QITER("4", 2, STAGE_G(Ag0, Bg, 224, 1));   // g=5
  QITER("4", 0, STAGE_G(Ag0, Bg, 256, 2));   // g=6
  QITER("4", 1, STAGE_G(Ag0, Bg, 288, 0));   // g=7
  QITER("4", 2, STAGE_G(Ag0, Bg, 320, 1));   // g=8
  QITER("4", 0, STAGE_G(Ag0, Bg, 352, 2));   // g=9  (stages L11)
  QITER("4", 1, STAGE_G(Ag1, Bg, 0, 0));     // g=10 (stages L12 = tile1 k0)
  QITER("4", 2, {});                          // g=11
  QEPI(mp * 256);                             // tile0 stores (8 wide)
  STAGE_G(Ag1, Bg, 32, 1);                    // L13
#pragma unroll
  for (int mt = 0; mt < 4; ++mt)
#pragma unroll
    for (int nt = 0; nt < 4; ++nt) acc[mt][nt] = (floatx4){0.f, 0.f, 0.f, 0.f};
  QITER("12", 0, STAGE_G(Ag1, Bg, 64, 2));   // g=12
  QITER("4", 1, STAGE_G(Ag1, Bg, 96, 0));    // g=13
  QITER("4", 2, STAGE_G(Ag1, Bg, 128, 1));   // g=14
  QITER("4", 0, STAGE_G(Ag1, Bg, 160, 2));   // g=15
  QITER("4", 1, STAGE_G(Ag1, Bg, 192, 0));   // g=16
  QITER("4", 2, STAGE_G(Ag1, Bg, 224, 1));   // g=17
  QITER("4", 0, STAGE_G(Ag1, Bg, 256, 2));   // g=18
  QITER("4", 1, STAGE_G(Ag1, Bg, 288, 0));   // g=19
  QITER("4", 2, STAGE_G(Ag1, Bg, 320, 1));   // g=20
  QITER("4", 0, STAGE_G(Ag1, Bg, 352, 2));   // g=21 (stages L23)
  QITER("4", 1, {});                          // g=22
  QITER("0", 2, {});                          // g=23
  QEPI(mp * 256 + 128);                       // tile1 stores
}

// ---------------- Kernel 3: out = attg @ WpT^T + b_proj (fp32 out; gate pre-folded)
// r7-proven 3-buf pipeline; stores only at kernel end (no vmcnt interplay).
__global__ __launch_bounds__(256) void k_proj(const unsigned short* __restrict__ A,
                                              const unsigned short* __restrict__ WpT,
                                              const float* __restrict__ bp,
                                              float* __restrict__ out) {
  __shared__ __align__(16) unsigned short As[3 * 4096];
  __shared__ __align__(16) unsigned short Bs[3 * 4096];
  const int t = threadIdx.x, lane = t & 63, w = t >> 6;
  const int wm = w >> 1, wn = w & 1;
  const int lq = lane & 15, lg = lane >> 4;
  const int swz = (blockIdx.x & 7) * 96 + (blockIdx.x >> 3);   // 768 = 8*96
  const int m0 = (swz / 3) * 128, n0 = (swz % 3) * 128;
  const unsigned short* Ag = A + (size_t)(m0 + w * 32) * 384;
  const unsigned short* Bg = WpT + (size_t)(n0 + w * 32) * 384;
  floatx4 acc[4][4] = {};

  STAGE_G(Ag, Bg, 0, 0);
  STAGE_G(Ag, Bg, 32, 1);
  QITER("4", 0, STAGE_G(Ag, Bg, 64, 2));
  QITER("4", 1, STAGE_G(Ag, Bg, 96, 0));
  QITER("4", 2, STAGE_G(Ag, Bg, 128, 1));
  QITER("4", 0, STAGE_G(Ag, Bg, 160, 2));
  QITER("4", 1, STAGE_G(Ag, Bg, 192, 0));
  QITER("4", 2, STAGE_G(Ag, Bg, 224, 1));
  QITER("4", 0, STAGE_G(Ag, Bg, 256, 2));
  QITER("4", 1, STAGE_G(Ag, Bg, 288, 0));
  QITER("4", 2, STAGE_G(Ag, Bg, 320, 1));
  QITER("4", 0, STAGE_G(Ag, Bg, 352, 2));
  QITER("4", 1, {});
  QITER("0", 2, {});

#pragma unroll
  for (int nt = 0; nt < 4; ++nt) {
    const int col = n0 + wn * 64 + nt * 16 + lq;
    const float bias = bp[col];
#pragma unroll
    for (int mt = 0; mt < 4; ++mt)
#pragma unroll
      for (int j = 0; j < 4; ++j) {
        const int row = m0 + wm * 64 + mt * 16 + lg * 4 + j;
        out[(size_t)row * 384 + col] = acc[mt][nt][j] + bias;
      }
  }
}

// ---------------- Kernel 2: windowed causal attention, packed qkv in, bf16 out [B][T][C]
__global__ __launch_bounds__(256) void k_attn(const unsigned short* __restrict__ qkv,
                                              unsigned short* __restrict__ attg) {
  __shared__ __align__(16) unsigned short Ks[128 * 72];      // [key][hd pad 64->72]
  __shared__ __align__(16) unsigned short Vt[48 * 152];      // [d][key pad 144->152]
  __shared__ __align__(16) unsigned short Ps[4 * 16 * 104];  // per-wave P [q][key pad]
  const int t = threadIdx.x;
  const int blk = blockIdx.x;
  const int tile = blk & 3;
  const int bh = blk >> 2;
  const int b = bh >> 3, h = bh & 7;
  const int base = tile * 64;
  const size_t kvoff = (size_t)bh * NT * ND;
  const unsigned short* qptr = qkv + kvoff;
  const unsigned short* kptr = qkv + (size_t)CPLANE + kvoff;
  const unsigned short* vptr = qkv + (size_t)2 * CPLANE + kvoff;

  if (t < 48) {
    bf16x8 z = {};
    *(bf16x8*)&Vt[t * 152 + 128] = z;
    *(bf16x8*)&Vt[t * 152 + 136] = z;
  }
  if (t < 128) {
    const int r = t, ka = base - 64 + r;
    unsigned short* dst = &Ks[r * 72];
    if (ka >= 0) {
      const unsigned short* src = kptr + (size_t)ka * ND;
#pragma unroll
      for (int i = 0; i < 6; ++i) *(bf16x8*)(dst + i * 8) = *(const bf16x8*)(src + i * 8);
      bf16x8 z = {};
      *(bf16x8*)(dst + 48) = z;
      *(bf16x8*)(dst + 56) = z;
    } else {
      bf16x8 z = {};
#pragma unroll
      for (int i = 0; i < 8; ++i) *(bf16x8*)(dst + i * 8) = z;
    }
  } else {
    const int r = t - 128, ka = base - 64 + r;
    if (ka >= 0) {
      const unsigned short* src = vptr + (size_t)ka * ND;
      bf16x8 vv[6];
#pragma unroll
      for (int i = 0; i < 6; ++i) vv[i] = *(const bf16x8*)(src + i * 8);
#pragma unroll
      for (int i = 0; i < 6; ++i)
#pragma unroll
        for (int j = 0; j < 8; ++j)
          Vt[(i * 8 + j) * 152 + r] = (unsigned short)vv[i][j];
    } else {
#pragma unroll
      for (int d = 0; d < 48; ++d) Vt[d * 152 + r] = 0;
    }
  }
  __syncthreads();

  const int lane = t & 63, w = t >> 6;
  const int lq = lane & 15, lg = lane >> 4;
  const int qs = base + w * 16;

  const unsigned short* qrow = qptr + (size_t)(qs + lq) * ND;
  bf16x8 aq0 = *(const bf16x8*)(qrow + lg * 8);
  bf16x8 aq1 = {};
  if (lg < 2) aq1 = *(const bf16x8*)(qrow + 32 + lg * 8);

  floatx4 s[5];
#pragma unroll
  for (int kt = 0; kt < 5; ++kt) {
    const unsigned short* kr = &Ks[(w * 16 + kt * 16 + lq) * 72];
    bf16x8 kb0 = *(const bf16x8*)(kr + lg * 8);
    bf16x8 kb1 = *(const bf16x8*)(kr + 32 + lg * 8);
    floatx4 z = {};
    z = __builtin_amdgcn_mfma_f32_16x16x32_bf16(aq0, kb0, z, 0, 0, 0);
    z = __builtin_amdgcn_mfma_f32_16x16x32_bf16(aq1, kb1, z, 0, 0, 0);
    s[kt] = z;
  }

  const float scale = 0.14433756729740643f;  // 1/sqrt(48)
  floatx4 pj[5];
#pragma unroll
  for (int j = 0; j < 4; ++j) {
    const int qa = qs + lg * 4 + j;
    float mx = -1e30f;
    float sv[5];
    bool ok[5];
#pragma unroll
    for (int kt = 0; kt < 5; ++kt) {
      const int ka = base - 64 + w * 16 + kt * 16 + lq;
      sv[kt] = s[kt][j] * scale;
      ok[kt] = (ka >= 0) && (ka <= qa) && (qa - ka <= 64);
      if (ok[kt]) mx = fmaxf(mx, sv[kt]);
    }
#pragma unroll
    for (int dd = 1; dd < 16; dd <<= 1) mx = fmaxf(mx, __shfl_xor(mx, dd));
    float sum = 0.f;
#pragma unroll
    for (int kt = 0; kt < 5; ++kt) {
      float p = ok[kt] ? __expf(sv[kt] - mx) : 0.f;
      pj[kt][j] = p;
      sum += p;
    }
#pragma unroll
    for (int dd = 1; dd < 16; dd <<= 1) sum += __shfl_xor(sum, dd);
    const float inv = 1.f / sum;
#pragma unroll
    for (int kt = 0; kt < 5; ++kt) pj[kt][j] *= inv;
  }

  unsigned short* pw = &Ps[w * 16 * 104];
#pragma unroll
  for (int kt = 0; kt < 5; ++kt)
#pragma unroll
    for (int j = 0; j < 4; ++j)
      pw[(lg * 4 + j) * 104 + kt * 16 + lq] = f2bf(pj[kt][j]);
#pragma unroll
  for (int j = 0; j < 4; ++j) pw[lq * 104 + 80 + lg * 4 + j] = 0;

  floatx4 o[3] = {};
#pragma unroll
  for (int c = 0; c < 3; ++c) {
    bf16x8 ap = *(const bf16x8*)&pw[lq * 104 + c * 32 + lg * 8];
#pragma unroll
    for (int nt = 0; nt < 3; ++nt) {
      bf16x8 av = *(const bf16x8*)&Vt[(nt * 16 + lq) * 152 + w * 16 + c * 32 + lg * 8];
      o[nt] = __builtin_amdgcn_mfma_f32_16x16x32_bf16(ap, av, o[nt], 0, 0, 0);
    }
  }
#pragma unroll
  for (int nt = 0; nt < 3; ++nt) {
    const int d = nt * 16 + lq;
    const int c = h * ND + d;
#pragma unroll
    for (int j = 0; j < 4; ++j) {
      const int tt = qs + lg * 4 + j;
      attg[((size_t)b * NT + tt) * NC + c] = f2bf(o[nt][j]);
    }
  }
}

extern "C" void kernel_launch(void* const* d_in, const int* in_sizes, int n_in,
                              void* d_out, int out_size, void* d_ws, size_t ws_size,
                              hipStream_t stream) {
  const float* x    = (const float*)d_in[0];
  const float* Wq   = (const float*)d_in[1];
  const float* bq   = (const float*)d_in[2];
  const float* Wp   = (const float*)d_in[3];
  const float* bp   = (const float*)d_in[4];
  const float* gate = (const float*)d_in[5];

  const size_t nx = (size_t)NB * NT * NC;                // 12,582,912
  unsigned short* attg = (unsigned short*)d_ws;
  unsigned short* xbf  = attg + nx;
  unsigned short* qkvp = xbf + nx;                       // packed [3][B][H][T][48]
  unsigned short* WqT  = qkvp + (size_t)3 * CPLANE;
  unsigned short* WpT  = WqT + (size_t)384 * 1152;
  float* out = (float*)d_out;

  k_prep<<<dim3(1680), 256, 0, stream>>>(x, Wq, Wp, gate, xbf, WqT, WpT);
  k_qkv<<<dim3(1152), 256, 0, stream>>>(xbf, WqT, bq, qkvp);
  k_attn<<<dim3(4096), 256, 0, stream>>>(qkvp, attg);
  k_proj<<<dim3(768), 256, 0, stream>>>(attg, WpT, bp, out);
}

// Round 10
// 113.276 us; speedup vs baseline: 1.0823x; 1.0744x over previous
//
#include <hip/hip_runtime.h>
#include <hip/hip_bf16.h>

typedef __attribute__((ext_vector_type(8))) short bf16x8;
typedef __attribute__((ext_vector_type(4))) float floatx4;

#define NB 128
#define NT 256
#define NC 384
#define NH 8
#define ND 48
#define CPLANE (128 * 8 * 256 * 48)  // elems per qkv component plane

static __device__ __forceinline__ unsigned short f2bf(float f) {
  __hip_bfloat16 h = __float2bfloat16(f);
  return __builtin_bit_cast(unsigned short, h);
}

static __device__ __forceinline__ void gload16(const unsigned short* g, unsigned short* l) {
  __builtin_amdgcn_global_load_lds(
      (const __attribute__((address_space(1))) void*)g,
      (__attribute__((address_space(3))) void*)l, 16, 0, 0);
}

// ---------------- Prep: W_qkv^T -> [1152][384] bf16, W_proj^T (gate folded) -> [384][384],
//                  x fp32 -> bf16.
__global__ __launch_bounds__(256) void k_prep(const float* __restrict__ x,
                                              const float* __restrict__ Wq,
                                              const float* __restrict__ Wp,
                                              const float* __restrict__ gate,
                                              unsigned short* __restrict__ xbf,
                                              unsigned short* __restrict__ WqT,
                                              unsigned short* __restrict__ WpT) {
  const int blk = blockIdx.x;
  const int t = threadIdx.x;
  if (blk < 144) {
    __shared__ float T[64][65];
    const float* src;
    unsigned short* dst;
    int N, kt, nt;
    const bool isWp = (blk >= 108);
    if (!isWp) { src = Wq; dst = WqT; N = 1152; kt = blk / 18; nt = blk % 18; }
    else { int b2 = blk - 108; src = Wp; dst = WpT; N = 384; kt = b2 / 6; nt = b2 % 6; }
    const int k0 = kt * 64, n0 = nt * 64;
    const int r = t >> 2, c = (t & 3) * 16;
    const float* s = src + (size_t)(k0 + r) * N + n0 + c;
#pragma unroll
    for (int i = 0; i < 4; ++i) *(float4*)&T[r][c + i * 4] = ((const float4*)s)[i];
    __syncthreads();
    float gv[16];
    if (isWp) {
#pragma unroll
      for (int i = 0; i < 4; ++i) *(float4*)&gv[i * 4] = ((const float4*)(gate + k0 + c))[i];
    } else {
#pragma unroll
      for (int i = 0; i < 16; ++i) gv[i] = 1.f;
    }
    unsigned short o[16];
#pragma unroll
    for (int i = 0; i < 16; ++i) o[i] = f2bf(T[c + i][r] * gv[i]);
    unsigned short* dp = dst + (size_t)(n0 + r) * 384 + k0 + c;
    *(bf16x8*)dp = *(bf16x8*)&o[0];
    *(bf16x8*)(dp + 8) = *(bf16x8*)&o[8];
  } else {
    const int n8 = (NB * NT * NC) / 8;
    int idx = (blk - 144) * 256 + t;
    const int stride = (gridDim.x - 144) * 256;
    for (; idx < n8; idx += stride) {
      const float* s = x + (size_t)idx * 8;
      float v[8];
      *(float4*)&v[0] = ((const float4*)s)[0];
      *(float4*)&v[4] = ((const float4*)s)[1];
      bf16x8 p;
#pragma unroll
      for (int i = 0; i < 8; ++i) p[i] = f2bf(v[i]);
      *(bf16x8*)(xbf + (size_t)idx * 8) = p;
    }
  }
}

// ====== r7-proven staging: 128x32 tile, source XOR-swizzle, linear LDS dest ======
#define STAGE_G(Ag, Bg, k0, buf)                                                     \
  {                                                                                  \
    const int r0_ = (lane >> 2), sw0_ = 8 * ((lane & 3) ^ ((r0_ >> 1) & 3));         \
    const int r1_ = r0_ + 16,    sw1_ = 8 * ((lane & 3) ^ ((r1_ >> 1) & 3));         \
    gload16((Ag) + (size_t)r0_ * 384 + (k0) + sw0_, As + (buf)*4096 + (w * 32) * 32);  \
    gload16((Ag) + (size_t)r1_ * 384 + (k0) + sw1_, As + (buf)*4096 + (w * 32 + 16) * 32); \
    gload16((Bg) + (size_t)r0_ * 384 + (k0) + sw0_, Bs + (buf)*4096 + (w * 32) * 32);  \
    gload16((Bg) + (size_t)r1_ * 384 + (k0) + sw1_, Bs + (buf)*4096 + (w * 32 + 16) * 32); \
  }

// r7-proven K-loop: 12 iters, 3 buffers, counted vmcnt(4), 2 barriers -> 1 per iter
#define GEMM_PIPE(Ag, Bg)                                                            \
  STAGE_G(Ag, Bg, 0, 0);                                                             \
  STAGE_G(Ag, Bg, 32, 1);                                                            \
  _Pragma("unroll") for (int t_ = 0; t_ < 12; ++t_) {                                \
    if (t_ < 11) asm volatile("s_waitcnt vmcnt(4)" ::: "memory");                    \
    else         asm volatile("s_waitcnt vmcnt(0)" ::: "memory");                    \
    __builtin_amdgcn_s_barrier();                                                    \
    if (t_ < 10) STAGE_G(Ag, Bg, (t_ + 2) * 32, (t_ + 2) % 3);                       \
    const unsigned short* Ac_ = As + (t_ % 3) * 4096;                                \
    const unsigned short* Bc_ = Bs + (t_ % 3) * 4096;                                \
    bf16x8 a_[4], b_[4];                                                             \
    _Pragma("unroll") for (int mt = 0; mt < 4; ++mt) {                               \
      const int R = wm * 64 + mt * 16 + lq;                                          \
      a_[mt] = *(const bf16x8*)&Ac_[R * 32 + 8 * (lg ^ ((R >> 1) & 3))];             \
    }                                                                                \
    _Pragma("unroll") for (int nt = 0; nt < 4; ++nt) {                               \
      const int R = wn * 64 + nt * 16 + lq;                                          \
      b_[nt] = *(const bf16x8*)&Bc_[R * 32 + 8 * (lg ^ ((R >> 1) & 3))];             \
    }                                                                                \
    _Pragma("unroll") for (int mt = 0; mt < 4; ++mt)                                 \
      _Pragma("unroll") for (int nt = 0; nt < 4; ++nt)                               \
        acc[mt][nt] = __builtin_amdgcn_mfma_f32_16x16x32_bf16(a_[mt], b_[nt], acc[mt][nt], 0, 0, 0); \
  }

// ---------------- Kernel 1: qkv = xb @ WqT^T + b_qkv -> packed bf16 [3][B][H][T][48]
// r7 core + end-of-kernel LDS-transpose epilogue (wide 16B packed stores, no
// stores inside the pipeline -> no vmcnt ledger interplay).
__global__ __launch_bounds__(256) void k_qkv(const unsigned short* __restrict__ xb,
                                             const unsigned short* __restrict__ WqT,
                                             const float* __restrict__ bq,
                                             unsigned short* __restrict__ qkv) {
  __shared__ __align__(16) unsigned short As[3 * 4096];
  __shared__ __align__(16) unsigned short Bs[3 * 4096];
  const int t = threadIdx.x, lane = t & 63, w = t >> 6;
  const int wm = w >> 1, wn = w & 1;
  const int lq = lane & 15, lg = lane >> 4;
  const int swz = (blockIdx.x & 7) * 288 + (blockIdx.x >> 3);  // 2304 = 8*288
  const int m0 = (swz / 9) * 128, n0 = (swz % 9) * 128;
  const int comp = n0 / 384;
  const unsigned short* Ag = xb + (size_t)(m0 + w * 32) * 384;
  const unsigned short* Bg = WqT + (size_t)(n0 + w * 32) * 384;
  floatx4 acc[4][4] = {};

  GEMM_PIPE(Ag, Bg);

  // epilogue: all reads of buf2 done (last QITER) -> barrier -> reuse buf2 slices
  __builtin_amdgcn_s_barrier();
  unsigned short* Ew = ((w < 2) ? As : Bs) + 2 * 4096 + (w & 1) * 2048;  // 2048 elems
#pragma unroll
  for (int p = 0; p < 4; ++p) {  // 16-row strip: transpose + bias, then 2 wide stores
#pragma unroll
    for (int nt = 0; nt < 4; ++nt) {
      const float bias = bq[n0 + wn * 64 + nt * 16 + lq];
#pragma unroll
      for (int j = 0; j < 4; ++j)
        Ew[(lg * 4 + j) * 72 + nt * 16 + lq] = f2bf(acc[p][nt][j] + bias);
    }
    asm volatile("s_waitcnt lgkmcnt(0)" ::: "memory");
    __builtin_amdgcn_sched_barrier(0);
#pragma unroll
    for (int cc = 0; cc < 2; ++cc) {
      const int c = cc * 64 + lane;
      const int r16 = c >> 3, k8 = c & 7;
      bf16x8 v = *(const bf16x8*)&Ew[r16 * 72 + k8 * 8];
      const int lc = n0 - comp * 384 + wn * 64 + k8 * 8;  // local col in comp
      const int hh = lc / 48, d0 = lc - hh * 48;          // 8-chunks never cross heads
      const int R = m0 + wm * 64 + p * 16 + r16;
      *(bf16x8*)(qkv + (size_t)comp * CPLANE +
                 (((size_t)((R >> 8) * 8 + hh) * 256 + (R & 255)) * 48 + d0)) = v;
    }
    asm volatile("s_waitcnt lgkmcnt(0)" ::: "memory");
    __builtin_amdgcn_sched_barrier(0);
  }
}

// ---------------- Kernel 3: out = attg @ WpT^T + b_proj (fp32 out; gate pre-folded)
__global__ __launch_bounds__(256) void k_proj(const unsigned short* __restrict__ A,
                                              const unsigned short* __restrict__ WpT,
                                              const float* __restrict__ bp,
                                              float* __restrict__ out) {
  __shared__ __align__(16) unsigned short As[3 * 4096];
  __shared__ __align__(16) unsigned short Bs[3 * 4096];
  const int t = threadIdx.x, lane = t & 63, w = t >> 6;
  const int wm = w >> 1, wn = w & 1;
  const int lq = lane & 15, lg = lane >> 4;
  const int swz = (blockIdx.x & 7) * 96 + (blockIdx.x >> 3);   // 768 = 8*96
  const int m0 = (swz / 3) * 128, n0 = (swz % 3) * 128;
  const unsigned short* Ag = A + (size_t)(m0 + w * 32) * 384;
  const unsigned short* Bg = WpT + (size_t)(n0 + w * 32) * 384;
  floatx4 acc[4][4] = {};

  GEMM_PIPE(Ag, Bg);

#pragma unroll
  for (int nt = 0; nt < 4; ++nt) {
    const int col = n0 + wn * 64 + nt * 16 + lq;
    const float bias = bp[col];
#pragma unroll
    for (int mt = 0; mt < 4; ++mt)
#pragma unroll
      for (int j = 0; j < 4; ++j) {
        const int row = m0 + wm * 64 + mt * 16 + lg * 4 + j;
        out[(size_t)row * 384 + col] = acc[mt][nt][j] + bias;
      }
  }
}

// ---------------- Kernel 2: windowed causal attention, packed qkv in, bf16 out [B][T][C]
__global__ __launch_bounds__(256) void k_attn(const unsigned short* __restrict__ qkv,
                                              unsigned short* __restrict__ attg) {
  __shared__ __align__(16) unsigned short Ks[128 * 72];      // [key][hd pad 64->72]
  __shared__ __align__(16) unsigned short Vt[48 * 152];      // [d][key pad 144->152]
  __shared__ __align__(16) unsigned short Ps[4 * 16 * 104];  // per-wave P [q][key pad]
  const int t = threadIdx.x;
  const int blk = blockIdx.x;
  const int tile = blk & 3;
  const int bh = blk >> 2;
  const int b = bh >> 3, h = bh & 7;
  const int base = tile * 64;
  const size_t kvoff = (size_t)bh * NT * ND;
  const unsigned short* qptr = qkv + kvoff;
  const unsigned short* kptr = qkv + (size_t)CPLANE + kvoff;
  const unsigned short* vptr = qkv + (size_t)2 * CPLANE + kvoff;

  if (t < 48) {
    bf16x8 z = {};
    *(bf16x8*)&Vt[t * 152 + 128] = z;
    *(bf16x8*)&Vt[t * 152 + 136] = z;
  }
  if (t < 128) {
    const int r = t, ka = base - 64 + r;
    unsigned short* dst = &Ks[r * 72];
    if (ka >= 0) {
      const unsigned short* src = kptr + (size_t)ka * ND;
#pragma unroll
      for (int i = 0; i < 6; ++i) *(bf16x8*)(dst + i * 8) = *(const bf16x8*)(src + i * 8);
      bf16x8 z = {};
      *(bf16x8*)(dst + 48) = z;
      *(bf16x8*)(dst + 56) = z;
    } else {
      bf16x8 z = {};
#pragma unroll
      for (int i = 0; i < 8; ++i) *(bf16x8*)(dst + i * 8) = z;
    }
  } else {
    const int r = t - 128, ka = base - 64 + r;
    if (ka >= 0) {
      const unsigned short* src = vptr + (size_t)ka * ND;
      bf16x8 vv[6];
#pragma unroll
      for (int i = 0; i < 6; ++i) vv[i] = *(const bf16x8*)(src + i * 8);
#pragma unroll
      for (int i = 0; i < 6; ++i)
#pragma unroll
        for (int j = 0; j < 8; ++j)
          Vt[(i * 8 + j) * 152 + r] = (unsigned short)vv[i][j];
    } else {
#pragma unroll
      for (int d = 0; d < 48; ++d) Vt[d * 152 + r] = 0;
    }
  }
  __syncthreads();

  const int lane = t & 63, w = t >> 6;
  const int lq = lane & 15, lg = lane >> 4;
  const int qs = base + w * 16;

  const unsigned short* qrow = qptr + (size_t)(qs + lq) * ND;
  bf16x8 aq0 = *(const bf16x8*)(qrow + lg * 8);
  bf16x8 aq1 = {};
  if (lg < 2) aq1 = *(const bf16x8*)(qrow + 32 + lg * 8);

  floatx4 s[5];
#pragma unroll
  for (int kt = 0; kt < 5; ++kt) {
    const unsigned short* kr = &Ks[(w * 16 + kt * 16 + lq) * 72];
    bf16x8 kb0 = *(const bf16x8*)(kr + lg * 8);
    bf16x8 kb1 = *(const bf16x8*)(kr + 32 + lg * 8);
    floatx4 z = {};
    z = __builtin_amdgcn_mfma_f32_16x16x32_bf16(aq0, kb0, z, 0, 0, 0);
    z = __builtin_amdgcn_mfma_f32_16x16x32_bf16(aq1, kb1, z, 0, 0, 0);
    s[kt] = z;
  }

  const float scale = 0.14433756729740643f;  // 1/sqrt(48)
  floatx4 pj[5];
#pragma unroll
  for (int j = 0; j < 4; ++j) {
    const int qa = qs + lg * 4 + j;
    float mx = -1e30f;
    float sv[5];
    bool ok[5];
#pragma unroll
    for (int kt = 0; kt < 5; ++kt) {
      const int ka = base - 64 + w * 16 + kt * 16 + lq;
      sv[kt] = s[kt][j] * scale;
      ok[kt] = (ka >= 0) && (ka <= qa) && (qa - ka <= 64);
      if (ok[kt]) mx = fmaxf(mx, sv[kt]);
    }
#pragma unroll
    for (int dd = 1; dd < 16; dd <<= 1) mx = fmaxf(mx, __shfl_xor(mx, dd));
    float sum = 0.f;
#pragma unroll
    for (int kt = 0; kt < 5; ++kt) {
      float p = ok[kt] ? __expf(sv[kt] - mx) : 0.f;
      pj[kt][j] = p;
      sum += p;
    }
#pragma unroll
    for (int dd = 1; dd < 16; dd <<= 1) sum += __shfl_xor(sum, dd);
    const float inv = 1.f / sum;
#pragma unroll
    for (int kt = 0; kt < 5; ++kt) pj[kt][j] *= inv;
  }

  unsigned short* pw = &Ps[w * 16 * 104];
#pragma unroll
  for (int kt = 0; kt < 5; ++kt)
#pragma unroll
    for (int j = 0; j < 4; ++j)
      pw[(lg * 4 + j) * 104 + kt * 16 + lq] = f2bf(pj[kt][j]);
#pragma unroll
  for (int j = 0; j < 4; ++j) pw[lq * 104 + 80 + lg * 4 + j] = 0;

  floatx4 o[3] = {};
#pragma unroll
  for (int c = 0; c < 3; ++c) {
    bf16x8 ap = *(const bf16x8*)&pw[lq * 104 + c * 32 + lg * 8];
#pragma unroll
    for (int nt = 0; nt < 3; ++nt) {
      bf16x8 av = *(const bf16x8*)&Vt[(nt * 16 + lq) * 152 + w * 16 + c * 32 + lg * 8];
      o[nt] = __builtin_amdgcn_mfma_f32_16x16x32_bf16(ap, av, o[nt], 0, 0, 0);
    }
  }
#pragma unroll
  for (int nt = 0; nt < 3; ++nt) {
    const int d = nt * 16 + lq;
    const int c = h * ND + d;
#pragma unroll
    for (int j = 0; j < 4; ++j) {
      const int tt = qs + lg * 4 + j;
      attg[((size_t)b * NT + tt) * NC + c] = f2bf(o[nt][j]);
    }
  }
}

extern "C" void kernel_launch(void* const* d_in, const int* in_sizes, int n_in,
                              void* d_out, int out_size, void* d_ws, size_t ws_size,
                              hipStream_t stream) {
  const float* x    = (const float*)d_in[0];
  const float* Wq   = (const float*)d_in[1];
  const float* bq   = (const float*)d_in[2];
  const float* Wp   = (const float*)d_in[3];
  const float* bp   = (const float*)d_in[4];
  const float* gate = (const float*)d_in[5];

  const size_t nx = (size_t)NB * NT * NC;                // 12,582,912
  unsigned short* attg = (unsigned short*)d_ws;
  unsigned short* xbf  = attg + nx;
  unsigned short* qkvp = xbf + nx;                       // packed [3][B][H][T][48]
  unsigned short* WqT  = qkvp + (size_t)3 * CPLANE;
  unsigned short* WpT  = WqT + (size_t)384 * 1152;
  float* out = (float*)d_out;

  k_prep<<<dim3(1680), 256, 0, stream>>>(x, Wq, Wp, gate, xbf, WqT, WpT);
  k_qkv<<<dim3(2304), 256, 0, stream>>>(xbf, WqT, bq, qkvp);
  k_attn<<<dim3(4096), 256, 0, stream>>>(qkvp, attg);
  k_proj<<<dim3(768), 256, 0, stream>>>(attg, WpT, bp, out);
}

// Round 12
// 110.929 us; speedup vs baseline: 1.1052x; 1.0212x over previous
//
#include <hip/hip_runtime.h>
#include <hip/hip_bf16.h>

typedef __attribute__((ext_vector_type(8))) short bf16x8;
typedef __attribute__((ext_vector_type(4))) float floatx4;

#define NB 128
#define NT 256
#define NC 384
#define NH 8
#define ND 48
#define CPLANE (128 * 8 * 256 * 48)  // elems per qkv component plane

static __device__ __forceinline__ unsigned short f2bf(float f) {
  __hip_bfloat16 h = __float2bfloat16(f);
  return __builtin_bit_cast(unsigned short, h);
}

static __device__ __forceinline__ void gload16(const unsigned short* g, unsigned short* l) {
  __builtin_amdgcn_global_load_lds(
      (const __attribute__((address_space(1))) void*)g,
      (__attribute__((address_space(3))) void*)l, 16, 0, 0);
}

// ---------------- Prep: W_qkv^T -> [1152][384] bf16, W_proj^T (gate folded) -> [384][384],
//                  x fp32 -> bf16.
__global__ __launch_bounds__(256) void k_prep(const float* __restrict__ x,
                                              const float* __restrict__ Wq,
                                              const float* __restrict__ Wp,
                                              const float* __restrict__ gate,
                                              unsigned short* __restrict__ xbf,
                                              unsigned short* __restrict__ WqT,
                                              unsigned short* __restrict__ WpT) {
  const int blk = blockIdx.x;
  const int t = threadIdx.x;
  if (blk < 144) {
    __shared__ float T[64][65];
    const float* src;
    unsigned short* dst;
    int N, kt, nt;
    const bool isWp = (blk >= 108);
    if (!isWp) { src = Wq; dst = WqT; N = 1152; kt = blk / 18; nt = blk % 18; }
    else { int b2 = blk - 108; src = Wp; dst = WpT; N = 384; kt = b2 / 6; nt = b2 % 6; }
    const int k0 = kt * 64, n0 = nt * 64;
    const int r = t >> 2, c = (t & 3) * 16;
    const float* s = src + (size_t)(k0 + r) * N + n0 + c;
#pragma unroll
    for (int i = 0; i < 4; ++i) *(float4*)&T[r][c + i * 4] = ((const float4*)s)[i];
    __syncthreads();
    float gv[16];
    if (isWp) {
#pragma unroll
      for (int i = 0; i < 4; ++i) *(float4*)&gv[i * 4] = ((const float4*)(gate + k0 + c))[i];
    } else {
#pragma unroll
      for (int i = 0; i < 16; ++i) gv[i] = 1.f;
    }
    unsigned short o[16];
#pragma unroll
    for (int i = 0; i < 16; ++i) o[i] = f2bf(T[c + i][r] * gv[i]);
    unsigned short* dp = dst + (size_t)(n0 + r) * 384 + k0 + c;
    *(bf16x8*)dp = *(bf16x8*)&o[0];
    *(bf16x8*)(dp + 8) = *(bf16x8*)&o[8];
  } else {
    const int n8 = (NB * NT * NC) / 8;
    int idx = (blk - 144) * 256 + t;
    const int stride = (gridDim.x - 144) * 256;
    for (; idx < n8; idx += stride) {
      const float* s = x + (size_t)idx * 8;
      float v[8];
      *(float4*)&v[0] = ((const float4*)s)[0];
      *(float4*)&v[4] = ((const float4*)s)[1];
      bf16x8 p;
#pragma unroll
      for (int i = 0; i < 8; ++i) p[i] = f2bf(v[i]);
      *(bf16x8*)(xbf + (size_t)idx * 8) = p;
    }
  }
}

// ====== r7-proven staging: 128x32 tile, source XOR-swizzle, linear LDS dest ======
#define STAGE_G(Ag, Bg, k0, buf)                                                     \
  {                                                                                  \
    const int r0_ = (lane >> 2), sw0_ = 8 * ((lane & 3) ^ ((r0_ >> 1) & 3));         \
    const int r1_ = r0_ + 16,    sw1_ = 8 * ((lane & 3) ^ ((r1_ >> 1) & 3));         \
    gload16((Ag) + (size_t)r0_ * 384 + (k0) + sw0_, As + (buf)*4096 + (w * 32) * 32);  \
    gload16((Ag) + (size_t)r1_ * 384 + (k0) + sw1_, As + (buf)*4096 + (w * 32 + 16) * 32); \
    gload16((Bg) + (size_t)r0_ * 384 + (k0) + sw0_, Bs + (buf)*4096 + (w * 32) * 32);  \
    gload16((Bg) + (size_t)r1_ * 384 + (k0) + sw1_, Bs + (buf)*4096 + (w * 32 + 16) * 32); \
  }

// r7-proven K-loop: 12 iters, 3 buffers, counted vmcnt(4), 1 barrier per iter
#define GEMM_PIPE(Ag, Bg)                                                            \
  STAGE_G(Ag, Bg, 0, 0);                                                             \
  STAGE_G(Ag, Bg, 32, 1);                                                            \
  _Pragma("unroll") for (int t_ = 0; t_ < 12; ++t_) {                                \
    if (t_ < 11) asm volatile("s_waitcnt vmcnt(4)" ::: "memory");                    \
    else         asm volatile("s_waitcnt vmcnt(0)" ::: "memory");                    \
    __builtin_amdgcn_s_barrier();                                                    \
    if (t_ < 10) STAGE_G(Ag, Bg, (t_ + 2) * 32, (t_ + 2) % 3);                       \
    const unsigned short* Ac_ = As + (t_ % 3) * 4096;                                \
    const unsigned short* Bc_ = Bs + (t_ % 3) * 4096;                                \
    bf16x8 a_[4], b_[4];                                                             \
    _Pragma("unroll") for (int mt = 0; mt < 4; ++mt) {                               \
      const int R = wm * 64 + mt * 16 + lq;                                          \
      a_[mt] = *(const bf16x8*)&Ac_[R * 32 + 8 * (lg ^ ((R >> 1) & 3))];             \
    }                                                                                \
    _Pragma("unroll") for (int nt = 0; nt < 4; ++nt) {                               \
      const int R = wn * 64 + nt * 16 + lq;                                          \
      b_[nt] = *(const bf16x8*)&Bc_[R * 32 + 8 * (lg ^ ((R >> 1) & 3))];             \
    }                                                                                \
    _Pragma("unroll") for (int mt = 0; mt < 4; ++mt)                                 \
      _Pragma("unroll") for (int nt = 0; nt < 4; ++nt)                               \
        acc[mt][nt] = __builtin_amdgcn_mfma_f32_16x16x32_bf16(a_[mt], b_[nt], acc[mt][nt], 0, 0, 0); \
  }

// ---------------- Kernel 1: qkv = xb @ WqT^T + b_qkv -> packed bf16 [3][B][H][T][48]
__global__ __launch_bounds__(256) void k_qkv(const unsigned short* __restrict__ xb,
                                             const unsigned short* __restrict__ WqT,
                                             const float* __restrict__ bq,
                                             unsigned short* __restrict__ qkv) {
  __shared__ __align__(16) unsigned short As[3 * 4096];
  __shared__ __align__(16) unsigned short Bs[3 * 4096];
  const int t = threadIdx.x, lane = t & 63, w = t >> 6;
  const int wm = w >> 1, wn = w & 1;
  const int lq = lane & 15, lg = lane >> 4;
  const int swz = (blockIdx.x & 7) * 288 + (blockIdx.x >> 3);  // 2304 = 8*288
  const int m0 = (swz / 9) * 128, n0 = (swz % 9) * 128;
  const int comp = n0 / 384;
  const unsigned short* Ag = xb + (size_t)(m0 + w * 32) * 384;
  const unsigned short* Bg = WqT + (size_t)(n0 + w * 32) * 384;
  floatx4 acc[4][4] = {};

  GEMM_PIPE(Ag, Bg);

  // epilogue: all reads of buf2 done (last QITER) -> barrier -> reuse buf2 slices
  __builtin_amdgcn_s_barrier();
  unsigned short* Ew = ((w < 2) ? As : Bs) + 2 * 4096 + (w & 1) * 2048;  // 2048 elems
#pragma unroll
  for (int p = 0; p < 4; ++p) {  // 16-row strip: transpose + bias, then 2 wide stores
#pragma unroll
    for (int nt = 0; nt < 4; ++nt) {
      const float bias = bq[n0 + wn * 64 + nt * 16 + lq];
#pragma unroll
      for (int j = 0; j < 4; ++j)
        Ew[(lg * 4 + j) * 72 + nt * 16 + lq] = f2bf(acc[p][nt][j] + bias);
    }
    asm volatile("s_waitcnt lgkmcnt(0)" ::: "memory");
    __builtin_amdgcn_sched_barrier(0);
#pragma unroll
    for (int cc = 0; cc < 2; ++cc) {
      const int c = cc * 64 + lane;
      const int r16 = c >> 3, k8 = c & 7;
      bf16x8 v = *(const bf16x8*)&Ew[r16 * 72 + k8 * 8];
      const int lc = n0 - comp * 384 + wn * 64 + k8 * 8;  // local col in comp
      const int hh = lc / 48, d0 = lc - hh * 48;          // 8-chunks never cross heads
      const int R = m0 + wm * 64 + p * 16 + r16;
      *(bf16x8*)(qkv + (size_t)comp * CPLANE +
                 (((size_t)((R >> 8) * 8 + hh) * 256 + (R & 255)) * 48 + d0)) = v;
    }
    asm volatile("s_waitcnt lgkmcnt(0)" ::: "memory");
    __builtin_amdgcn_sched_barrier(0);
  }
}

// ---------------- Kernel 3: out = attg @ WpT^T + b_proj (fp32 out; gate pre-folded)
__global__ __launch_bounds__(256) void k_proj(const unsigned short* __restrict__ A,
                                              const unsigned short* __restrict__ WpT,
                                              const float* __restrict__ bp,
                                              float* __restrict__ out) {
  __shared__ __align__(16) unsigned short As[3 * 4096];
  __shared__ __align__(16) unsigned short Bs[3 * 4096];
  const int t = threadIdx.x, lane = t & 63, w = t >> 6;
  const int wm = w >> 1, wn = w & 1;
  const int lq = lane & 15, lg = lane >> 4;
  const int swz = (blockIdx.x & 7) * 96 + (blockIdx.x >> 3);   // 768 = 8*96
  const int m0 = (swz / 3) * 128, n0 = (swz % 3) * 128;
  const unsigned short* Ag = A + (size_t)(m0 + w * 32) * 384;
  const unsigned short* Bg = WpT + (size_t)(n0 + w * 32) * 384;
  floatx4 acc[4][4] = {};

  GEMM_PIPE(Ag, Bg);

#pragma unroll
  for (int nt = 0; nt < 4; ++nt) {
    const int col = n0 + wn * 64 + nt * 16 + lq;
    const float bias = bp[col];
#pragma unroll
    for (int mt = 0; mt < 4; ++mt)
#pragma unroll
      for (int j = 0; j < 4; ++j) {
        const int row = m0 + wm * 64 + mt * 16 + lg * 4 + j;
        out[(size_t)row * 384 + col] = acc[mt][nt][j] + bias;
      }
  }
}

// ---------------- Kernel 2: windowed causal attention, one block per (b,h).
// K/V staged ONCE for all 256 queries; each wave loops 4 query-subtiles.
// Hardened vs r11: __syncthreads() at the end of every subtile iteration.
__global__ __launch_bounds__(256) void k_attn(const unsigned short* __restrict__ qkv,
                                              unsigned short* __restrict__ attg) {
  __shared__ __align__(16) unsigned short Ks[256 * 72];      // [key][hd pad 64->72]
  __shared__ __align__(16) unsigned short Vt[48 * 280];      // [d][key pad 256->280]
  __shared__ __align__(16) unsigned short Ps[4 * 16 * 104];  // per-wave P [q][key pad]
  const int t = threadIdx.x;
  const int bh = blockIdx.x;
  const int b = bh >> 3, h = bh & 7;
  const size_t kvoff = (size_t)bh * NT * ND;
  const unsigned short* qptr = qkv + kvoff;
  const unsigned short* kptr = qkv + (size_t)CPLANE + kvoff;
  const unsigned short* vptr = qkv + (size_t)2 * CPLANE + kvoff;

  {  // stage K row t (all 256 keys), hd zero-padded 48..63
    const unsigned short* src = kptr + (size_t)t * ND;
    unsigned short* dst = &Ks[t * 72];
#pragma unroll
    for (int i = 0; i < 6; ++i) *(bf16x8*)(dst + i * 8) = *(const bf16x8*)(src + i * 8);
    bf16x8 z = {};
    *(bf16x8*)(dst + 48) = z;
    *(bf16x8*)(dst + 56) = z;
  }
  {  // stage V^T: thread t = key t, scatter 48 scalars
    const unsigned short* src = vptr + (size_t)t * ND;
    bf16x8 vv[6];
#pragma unroll
    for (int i = 0; i < 6; ++i) vv[i] = *(const bf16x8*)(src + i * 8);
#pragma unroll
    for (int i = 0; i < 6; ++i)
#pragma unroll
      for (int j = 0; j < 8; ++j)
        Vt[(i * 8 + j) * 280 + t] = (unsigned short)vv[i][j];
  }
  if (t < 144) {  // zero V pad cols 256..279
    bf16x8 z = {};
    *(bf16x8*)&Vt[(t / 3) * 280 + 256 + (t % 3) * 8] = z;
  }
  __syncthreads();

  const int lane = t & 63, w = t >> 6;
  const int lq = lane & 15, lg = lane >> 4;
  const float scale = 0.14433756729740643f;  // 1/sqrt(48)
  unsigned short* pw = &Ps[w * 16 * 104];

  for (int s = 0; s < 4; ++s) {
    const int qs = s * 64 + w * 16;
    const int kstart = (qs >= 64) ? (qs - 64) : 0;

    const unsigned short* qrow = qptr + (size_t)(qs + lq) * ND;
    bf16x8 aq0 = *(const bf16x8*)(qrow + lg * 8);
    bf16x8 aq1 = {};
    if (lg < 2) aq1 = *(const bf16x8*)(qrow + 32 + lg * 8);

    floatx4 sv4[5];
#pragma unroll
    for (int kt = 0; kt < 5; ++kt) {
      const unsigned short* kr = &Ks[(kstart + kt * 16 + lq) * 72];
      bf16x8 kb0 = *(const bf16x8*)(kr + lg * 8);
      bf16x8 kb1 = *(const bf16x8*)(kr + 32 + lg * 8);
      floatx4 z = {};
      z = __builtin_amdgcn_mfma_f32_16x16x32_bf16(aq0, kb0, z, 0, 0, 0);
      z = __builtin_amdgcn_mfma_f32_16x16x32_bf16(aq1, kb1, z, 0, 0, 0);
      sv4[kt] = z;
    }

    floatx4 pj[5];
#pragma unroll
    for (int j = 0; j < 4; ++j) {
      const int qa = qs + lg * 4 + j;
      float mx = -1e30f;
      float sv[5];
      bool ok[5];
#pragma unroll
      for (int kt = 0; kt < 5; ++kt) {
        const int ka = kstart + kt * 16 + lq;
        sv[kt] = sv4[kt][j] * scale;
        ok[kt] = (ka <= qa) && (qa - ka <= 64);
        if (ok[kt]) mx = fmaxf(mx, sv[kt]);
      }
#pragma unroll
      for (int dd = 1; dd < 16; dd <<= 1) mx = fmaxf(mx, __shfl_xor(mx, dd));
      float sum = 0.f;
#pragma unroll
      for (int kt = 0; kt < 5; ++kt) {
        float p = ok[kt] ? __expf(sv[kt] - mx) : 0.f;
        pj[kt][j] = p;
        sum += p;
      }
#pragma unroll
      for (int dd = 1; dd < 16; dd <<= 1) sum += __shfl_xor(sum, dd);
      const float inv = 1.f / sum;
#pragma unroll
      for (int kt = 0; kt < 5; ++kt) pj[kt][j] *= inv;
    }

#pragma unroll
    for (int kt = 0; kt < 5; ++kt)
#pragma unroll
      for (int j = 0; j < 4; ++j)
        pw[(lg * 4 + j) * 104 + kt * 16 + lq] = f2bf(pj[kt][j]);
#pragma unroll
    for (int j = 0; j < 4; ++j) pw[lq * 104 + 80 + lg * 4 + j] = 0;

    floatx4 o[3] = {};
#pragma unroll
    for (int c = 0; c < 3; ++c) {
      bf16x8 ap = *(const bf16x8*)&pw[lq * 104 + c * 32 + lg * 8];
#pragma unroll
      for (int nt = 0; nt < 3; ++nt) {
        bf16x8 av = *(const bf16x8*)&Vt[(nt * 16 + lq) * 280 + kstart + c * 32 + lg * 8];
        o[nt] = __builtin_amdgcn_mfma_f32_16x16x32_bf16(ap, av, o[nt], 0, 0, 0);
      }
    }
#pragma unroll
    for (int nt = 0; nt < 3; ++nt) {
      const int d = nt * 16 + lq;
      const int c = h * ND + d;
#pragma unroll
      for (int j = 0; j < 4; ++j) {
        const int tt = qs + lg * 4 + j;
        attg[((size_t)b * NT + tt) * NC + c] = f2bf(o[nt][j]);
      }
    }
    __syncthreads();  // hardening: no inter-wave overlap across subtile iterations
  }
}

extern "C" void kernel_launch(void* const* d_in, const int* in_sizes, int n_in,
                              void* d_out, int out_size, void* d_ws, size_t ws_size,
                              hipStream_t stream) {
  const float* x    = (const float*)d_in[0];
  const float* Wq   = (const float*)d_in[1];
  const float* bq   = (const float*)d_in[2];
  const float* Wp   = (const float*)d_in[3];
  const float* bp   = (const float*)d_in[4];
  const float* gate = (const float*)d_in[5];

  const size_t nx = (size_t)NB * NT * NC;                // 12,582,912
  unsigned short* attg = (unsigned short*)d_ws;
  unsigned short* xbf  = attg + nx;
  unsigned short* qkvp = xbf + nx;                       // packed [3][B][H][T][48]
  unsigned short* WqT  = qkvp + (size_t)3 * CPLANE;
  unsigned short* WpT  = WqT + (size_t)384 * 1152;
  float* out = (float*)d_out;

  k_prep<<<dim3(1680), 256, 0, stream>>>(x, Wq, Wp, gate, xbf, WqT, WpT);
  k_qkv<<<dim3(2304), 256, 0, stream>>>(xbf, WqT, bq, qkvp);
  k_attn<<<dim3(1024), 256, 0, stream>>>(qkvp, attg);
  k_proj<<<dim3(768), 256, 0, stream>>>(attg, WpT, bp, out);
}